// Round 4
// baseline (184.939 us; speedup 1.0000x reference)
//
#include <hip/hip_runtime.h>

typedef unsigned short u16;
typedef unsigned int u32;
typedef short bf16x8 __attribute__((ext_vector_type(8)));
typedef float f32x4 __attribute__((ext_vector_type(4)));
typedef u16 u16x4 __attribute__((ext_vector_type(4)));

#define NAG 32
#define STATE 512
#define EMBED 64
#define TB 32   // samples per block; 256 threads (4 waves); grid = 1024 = 4 blocks/CU

// d_ws bf16 layout (u16 element offsets).
#define OFF_W1L1 0
#define OFF_W2L1 32768
#define OFF_B1W  65536
#define OFF_B2L1 98304
#define OFF_W1L2 131072
#define OFF_W2L2 262144
#define WS_TOTAL 266240

// smem layout (u16 offsets). Total 15872 u16 = 31 KB -> 4 blocks/CU (grid-limited),
// i.e. 16 waves/CU = 4 waves/SIMD with VGPR <= 128.
#define Y_OFF    0            // y[32][200]: [0,64) h1 | [64,128) h2 | [128,192) b1v->hidden
#define Y_STR    200
#define SB_OFF   6400         // sb[2][32][72] bf16 state K-slices
#define SB_STR   72
#define SB_BUF   (32 * 72)
#define W1BS_OFF 11008        // w1l2b bf16 [2048]
#define QST_OFF  13056        // qs^T bf16 [32 agents][36]
#define QST_STR  36
#define PBUF_OFF 6400         // phase-B partials [4][32][72] — overlays sb/w1bs/qst (dead)
#define PBUF_STR 72
#define PBUF_WV  (32 * 72)
#define QACC_OFF  15616       // f32[32]
#define QACC2_OFF 15680       // f32[32]
#define B2WV_OFF  15744       // f32[64]
#define SMEM_U16  15872

__device__ __forceinline__ float bf2f(u16 u) {
    u32 i = ((u32)u) << 16; float f;
    __builtin_memcpy(&f, &i, 4); return f;
}
__device__ __forceinline__ u16 f2bf(float f) {
    u32 i; __builtin_memcpy(&i, &f, 4);
    return (u16)((i + 0x8000u) >> 16);
}
__device__ __forceinline__ bf16x8 ld8(const u16* p) {
    return *reinterpret_cast<const bf16x8*>(p);
}
__device__ __forceinline__ bf16x8 cvt8(f32x4 a, f32x4 b) {
    bf16x8 r;
#pragma unroll
    for (int i = 0; i < 4; ++i) r[i]     = (short)f2bf(a[i]);
#pragma unroll
    for (int i = 0; i < 4; ++i) r[i + 4] = (short)f2bf(b[i]);
    return r;
}

__global__ __launch_bounds__(256) void cvt_weights(
    const float* __restrict__ w1l1w, const float* __restrict__ w2l1w,
    const float* __restrict__ b1w,   const float* __restrict__ b2l1w,
    const float* __restrict__ w1l2w, const float* __restrict__ w2l2w,
    u16* __restrict__ ws)
{
    int idx = blockIdx.x * 256 + threadIdx.x;
    const float* src; int off;
    if      (idx < OFF_W2L1)  { src = w1l1w; off = OFF_W1L1; }
    else if (idx < OFF_B1W)   { src = w2l1w; off = OFF_W2L1; }
    else if (idx < OFF_B2L1)  { src = b1w;   off = OFF_B1W;  }
    else if (idx < OFF_W1L2)  { src = b2l1w; off = OFF_B2L1; }
    else if (idx < OFF_W2L2)  { src = w1l2w; off = OFF_W1L2; }
    else if (idx < WS_TOTAL)  { src = w2l2w; off = OFF_W2L2; }
    else return;
    ws[idx] = f2bf(src[idx - off]);
}

// TB=32 / 4-wave / 4-blocks-per-CU decomposition (latency hiding via 4 waves/SIMD
// at full <=128 VGPR budget; R3's lesson: never force the 64-VGPR class):
//  Phase A: wave w owns 64 features [64w,64w+64) x all 32 samples; weights direct
//           from global (L2-resident), states staged in LDS bf16 double-buffered.
//           wave 3 (hb features) dots with b2l2w immediately -> qacc2.
//  Phase B: wave w owns agents [8w,8w+8) x all 32 samples; partials -> pbuf,
//           one cross-wave reduction -> hidden (elu) in place over b1v.
//  Phase C: waves 0-1 (16 samples each): w2 = |h2 @ W2l2^T + b| dot hidden.
//  Phase D: out = qacc + qacc2 + b2l2b.
__global__ __launch_bounds__(256, 4) void qmix_kernel(
    const float* __restrict__ qs,    const float* __restrict__ st,
    const u16*  __restrict__ wsb,
    const float* __restrict__ w1l1b, const float* __restrict__ w1l2b,
    const float* __restrict__ w2l1b, const float* __restrict__ w2l2b,
    const float* __restrict__ b1b,   const float* __restrict__ b2l1b,
    const float* __restrict__ b2l2w, const float* __restrict__ b2l2b,
    float* __restrict__ out)
{
    __shared__ u16 smem[SMEM_U16];
    float* qaccF  = (float*)(smem + QACC_OFF);
    float* qacc2F = (float*)(smem + QACC2_OFF);
    float* b2wvF  = (float*)(smem + B2WV_OFF);

    const int t    = threadIdx.x;
    const int wave = t >> 6, lane = t & 63;
    const int m = lane & 15, quad = lane >> 4;
    const int sbase = blockIdx.x * TB;

    // ---- prologue staging ----
    if (t < 64) b2wvF[t] = b2l2w[t];
    if (t < 128) {   // qs -> bf16 transposed [agent][sample]; 32x32 block
        const float* qp = qs + (size_t)sbase * NAG + t * 8;
        f32x4 q0 = *reinterpret_cast<const f32x4*>(qp);
        f32x4 q1 = *reinterpret_cast<const f32x4*>(qp + 4);
        const int s = t >> 2, a0 = (t & 3) * 8;
#pragma unroll
        for (int j = 0; j < 4; ++j) smem[QST_OFF + (a0 + j) * QST_STR + s]     = f2bf(q0[j]);
#pragma unroll
        for (int j = 0; j < 4; ++j) smem[QST_OFF + (a0 + 4 + j) * QST_STR + s] = f2bf(q1[j]);
    }
    {   // w1l2b -> bf16 (all 256 threads, 8 each)
        f32x4 w0 = *reinterpret_cast<const f32x4*>(w1l2b + t * 8);
        f32x4 w1 = *reinterpret_cast<const f32x4*>(w1l2b + t * 8 + 4);
        *reinterpret_cast<bf16x8*>(&smem[W1BS_OFF + t * 8]) = cvt8(w0, w1);
    }

    // states staging: thread owns (sample t>>3, chunk t&7): one bf16x8 per slice
    const int ss1 = t >> 3, c8 = t & 7;
    const float* stb = st + (size_t)sbase * STATE;
    {   // stage slice 0
        const float* g1 = stb + (size_t)ss1 * STATE + c8 * 8;
        f32x4 a0 = *reinterpret_cast<const f32x4*>(g1);
        f32x4 a1 = *reinterpret_cast<const f32x4*>(g1 + 4);
        *reinterpret_cast<bf16x8*>(&smem[SB_OFF + ss1 * SB_STR + c8 * 8]) = cvt8(a0, a1);
    }

    // ---- Phase A: wave w owns features [64w, 64w+64) ----
    const u16* wAw = wsb + (size_t)(wave * 64) * STATE;
    __syncthreads();   // sb[0] + prologue visible

    f32x4 acc[2][4] = {};
#pragma unroll
    for (int ks = 0; ks < 8; ++ks) {
        // current-slice weight fragments (single-buffered; 4-wave TLP hides latency)
        bf16x8 bfr[4][2];
#pragma unroll
        for (int ot = 0; ot < 4; ++ot) {
            const u16* wr = wAw + (size_t)(ot * 16 + m) * STATE + ks * 64 + quad * 8;
            bfr[ot][0] = ld8(wr);
            bfr[ot][1] = ld8(wr + 32);
        }
        // next-slice state prefetch
        f32x4 sa0 = {}, sa1 = {};
        if (ks < 7) {
            const float* g1 = stb + (size_t)ss1 * STATE + (ks + 1) * 64 + c8 * 8;
            sa0 = *reinterpret_cast<const f32x4*>(g1);
            sa1 = *reinterpret_cast<const f32x4*>(g1 + 4);
        }
        const u16* sbc = smem + SB_OFF + (ks & 1) * SB_BUF;
#pragma unroll
        for (int st2 = 0; st2 < 2; ++st2) {
            const int row = st2 * 16 + m;
            bf16x8 af0 = ld8(&sbc[row * SB_STR + quad * 8]);
            bf16x8 af1 = ld8(&sbc[row * SB_STR + (quad + 4) * 8]);
#pragma unroll
            for (int ot = 0; ot < 4; ++ot)
                acc[st2][ot] = __builtin_amdgcn_mfma_f32_16x16x32_bf16(af0, bfr[ot][0], acc[st2][ot], 0, 0, 0);
#pragma unroll
            for (int ot = 0; ot < 4; ++ot)
                acc[st2][ot] = __builtin_amdgcn_mfma_f32_16x16x32_bf16(af1, bfr[ot][1], acc[st2][ot], 0, 0, 0);
        }
        if (ks < 7) {
            u16* dst = smem + SB_OFF + ((ks + 1) & 1) * SB_BUF;
            *reinterpret_cast<bf16x8*>(&dst[ss1 * SB_STR + c8 * 8]) = cvt8(sa0, sa1);
            __syncthreads();
        }
    }

    // ---- Phase A epilogue: wave = group (0:h1, 1:h2, 2:b1v, 3:hb) ----
    if (wave < 3) {
        const float* barr = (wave == 0) ? w1l1b : (wave == 1) ? w2l1b : b1b;
        const bool isrelu = (wave != 2);
        float wb[4];
#pragma unroll
        for (int ot = 0; ot < 4; ++ot) wb[ot] = barr[ot * 16 + m];
#pragma unroll
        for (int st2 = 0; st2 < 2; ++st2)
#pragma unroll
            for (int ot = 0; ot < 4; ++ot)
#pragma unroll
                for (int r = 0; r < 4; ++r) {
                    float v = acc[st2][ot][r] + wb[ot];
                    if (isrelu) v = fmaxf(v, 0.f);
                    smem[Y_OFF + (st2 * 16 + quad * 4 + r) * Y_STR + wave * 64 + ot * 16 + m] = f2bf(v);
                }
    } else {
        // hb = relu(states @ b2l1 + b) dotted with b2l2w -> qacc2
        float wb[4], bw[4];
#pragma unroll
        for (int ot = 0; ot < 4; ++ot) wb[ot] = b2l1b[ot * 16 + m];
#pragma unroll
        for (int ot = 0; ot < 4; ++ot) bw[ot] = b2wvF[ot * 16 + m];
#pragma unroll
        for (int st2 = 0; st2 < 2; ++st2)
#pragma unroll
            for (int r = 0; r < 4; ++r) {
                float pd = 0.f;
#pragma unroll
                for (int ot = 0; ot < 4; ++ot)
                    pd += fmaxf(acc[st2][ot][r] + wb[ot], 0.f) * bw[ot];
#pragma unroll
                for (int off = 1; off < 16; off <<= 1) pd += __shfl_xor(pd, off, 64);
                if (m == 0) qacc2F[st2 * 16 + quad * 4 + r] = pd;
            }
    }
    __syncthreads();   // y + qacc2 ready

    // ---- Phase B: wave w owns agents [8w,8w+8) x all 32 samples ----
    bf16x8 h1f[2][2];
#pragma unroll
    for (int st2 = 0; st2 < 2; ++st2) {
        const int row = st2 * 16 + m;
        h1f[st2][0] = ld8(&smem[Y_OFF + row * Y_STR + quad * 8]);
        h1f[st2][1] = ld8(&smem[Y_OFF + row * Y_STR + 32 + quad * 8]);
    }

    const u16* wB = wsb + OFF_W1L2 + (size_t)(wave * 8) * 64 * EMBED;
    f32x4 hacc[2][4] = {};
#pragma unroll
    for (int ag = 0; ag < 8; ++ag) {
        const int a = wave * 8 + ag;
        bf16x8 bb[4][2];
#pragma unroll
        for (int ot = 0; ot < 4; ++ot) {
            const u16* wr = wB + (size_t)(ag * 64 + ot * 16 + m) * EMBED + quad * 8;
            bb[ot][0] = ld8(wr);
            bb[ot][1] = ld8(wr + 32);
        }
        float bias[4];
#pragma unroll
        for (int ot = 0; ot < 4; ++ot) bias[ot] = bf2f(smem[W1BS_OFF + a * EMBED + ot * 16 + m]);
#pragma unroll
        for (int st2 = 0; st2 < 2; ++st2) {
            u16x4 qv = *reinterpret_cast<const u16x4*>(
                &smem[QST_OFF + a * QST_STR + st2 * 16 + quad * 4]);
#pragma unroll
            for (int ot = 0; ot < 4; ++ot) {
                f32x4 p = {};
                p = __builtin_amdgcn_mfma_f32_16x16x32_bf16(h1f[st2][0], bb[ot][0], p, 0, 0, 0);
                p = __builtin_amdgcn_mfma_f32_16x16x32_bf16(h1f[st2][1], bb[ot][1], p, 0, 0, 0);
#pragma unroll
                for (int r = 0; r < 4; ++r)
                    hacc[st2][ot][r] += bf2f((u16)qv[r]) * fabsf(p[r] + bias[ot]);
            }
        }
    }
    __syncthreads();   // qst/w1bs/sb reads done -> safe to overlay pbuf

#pragma unroll
    for (int st2 = 0; st2 < 2; ++st2)
#pragma unroll
        for (int ot = 0; ot < 4; ++ot)
#pragma unroll
            for (int r = 0; r < 4; ++r)
                smem[PBUF_OFF + wave * PBUF_WV
                     + (st2 * 16 + quad * 4 + r) * PBUF_STR + ot * 16 + m]
                    = f2bf(hacc[st2][ot][r]);
    __syncthreads();   // partials in

    // ---- reduction: hidden = elu(sum_waves pbuf + b1v), in place over b1v ----
    {
        const int s  = t >> 3;             // 0..31
        const int eb = (t & 7) * 8;        // 0..56
        float v[8];
#pragma unroll
        for (int j = 0; j < 8; ++j) v[j] = 0.f;
#pragma unroll
        for (int pw = 0; pw < 4; ++pw) {
            u16x4 x0 = *reinterpret_cast<const u16x4*>(
                &smem[PBUF_OFF + pw * PBUF_WV + s * PBUF_STR + eb]);
            u16x4 x1 = *reinterpret_cast<const u16x4*>(
                &smem[PBUF_OFF + pw * PBUF_WV + s * PBUF_STR + eb + 4]);
#pragma unroll
            for (int j = 0; j < 4; ++j) v[j]     += bf2f((u16)x0[j]);
#pragma unroll
            for (int j = 0; j < 4; ++j) v[4 + j] += bf2f((u16)x1[j]);
        }
        bf16x8 bv = ld8(&smem[Y_OFF + s * Y_STR + 128 + eb]);
        bf16x8 o;
#pragma unroll
        for (int j = 0; j < 8; ++j) {
            float h = v[j] + bf2f((u16)bv[j]);
            h = (h > 0.f) ? h : (__expf(h) - 1.f);
            o[j] = (short)f2bf(h);
        }
        *reinterpret_cast<bf16x8*>(&smem[Y_OFF + s * Y_STR + 128 + eb]) = o;
    }
    __syncthreads();   // hidden ready

    // ---- Phase C (waves 0-1): w2 = |h2 @ W2l2^T + b|; q = sum_e hidden*w2 ----
    if (wave < 2) {
        const int s0 = wave * 16;
        bf16x8 h2f0 = ld8(&smem[Y_OFF + (s0 + m) * Y_STR + 64 + quad * 8]);
        bf16x8 h2f1 = ld8(&smem[Y_OFF + (s0 + m) * Y_STR + 96 + quad * 8]);

        f32x4 qp = {};
#pragma unroll
        for (int tp = 0; tp < 4; ++tp) {
            const u16* wc = wsb + OFF_W2L2 + (size_t)(tp * 16 + m) * EMBED + quad * 8;
            bf16x8 c0 = ld8(wc);
            bf16x8 c1 = ld8(wc + 32);
            f32x4 p = {};
            p = __builtin_amdgcn_mfma_f32_16x16x32_bf16(h2f0, c0, p, 0, 0, 0);
            p = __builtin_amdgcn_mfma_f32_16x16x32_bf16(h2f1, c1, p, 0, 0, 0);
            const float bias = w2l2b[tp * 16 + m];
#pragma unroll
            for (int r = 0; r < 4; ++r)
                qp[r] += bf2f(smem[Y_OFF + (s0 + quad * 4 + r) * Y_STR + 128 + tp * 16 + m])
                         * fabsf(p[r] + bias);
        }
#pragma unroll
        for (int off = 1; off < 16; off <<= 1) {
#pragma unroll
            for (int r = 0; r < 4; ++r) qp[r] += __shfl_xor(qp[r], off, 64);
        }
        if (m == 0) {
#pragma unroll
            for (int r = 0; r < 4; ++r) qaccF[s0 + quad * 4 + r] = qp[r];
        }
    }
    __syncthreads();   // qacc ready

    // ---- Phase D ----
    if (t < TB) out[sbase + t] = qaccF[t] + qacc2F[t] + b2l2b[0];
}

extern "C" void kernel_launch(void* const* d_in, const int* in_sizes, int n_in,
                              void* d_out, int out_size, void* d_ws, size_t ws_size,
                              hipStream_t stream)
{
    const float* qs    = (const float*)d_in[0];
    const float* st    = (const float*)d_in[1];
    const float* w1l1w = (const float*)d_in[2];
    const float* w1l1b = (const float*)d_in[3];
    const float* w1l2w = (const float*)d_in[4];
    const float* w1l2b = (const float*)d_in[5];
    const float* w2l1w = (const float*)d_in[6];
    const float* w2l1b = (const float*)d_in[7];
    const float* w2l2w = (const float*)d_in[8];
    const float* w2l2b = (const float*)d_in[9];
    const float* b1w   = (const float*)d_in[10];
    const float* b1b   = (const float*)d_in[11];
    const float* b2l1w = (const float*)d_in[12];
    const float* b2l1b = (const float*)d_in[13];
    const float* b2l2w = (const float*)d_in[14];
    const float* b2l2b = (const float*)d_in[15];

    u16* wsb = (u16*)d_ws;

    cvt_weights<<<(WS_TOTAL + 255) / 256, 256, 0, stream>>>(
        w1l1w, w2l1w, b1w, b2l1w, w1l2w, w2l2w, wsb);

    int B = in_sizes[0] / NAG;        // 32768
    int grid = B / TB;                // 1024 blocks -> 4 blocks/CU, single round
    qmix_kernel<<<grid, 256, 0, stream>>>(
        qs, st, wsb,
        w1l1b, w1l2b, w2l1b, w2l2b, b1b, b2l1b, b2l2w, b2l2b,
        (float*)d_out);
}

// Round 7
// 147.511 us; speedup vs baseline: 1.2537x; 1.2537x over previous
//
#include <hip/hip_runtime.h>

typedef unsigned short u16;
typedef unsigned int u32;
typedef short bf16x8 __attribute__((ext_vector_type(8)));
typedef float f32x4 __attribute__((ext_vector_type(4)));
typedef u16 u16x4 __attribute__((ext_vector_type(4)));

#define NAG 32
#define STATE 512
#define EMBED 64
#define TB 64   // samples per block; 256 threads (4 waves); grid = 512 = 2 blocks/CU

// d_ws bf16 layout (u16 element offsets).
#define OFF_W1L1 0
#define OFF_W2L1 32768
#define OFF_B1W  65536
#define OFF_B2L1 98304
#define OFF_W1L2 131072
#define OFF_W2L2 262144
#define WS_TOTAL 266240

// smem layout (u16 offsets). Total 38400 u16 = 75 KB -> 2 blocks/CU.
#define WBUF_OFF 0        // weight slice [256][64]; wave w owns rows [64w, 64w+64)
#define SB_OFF   16384    // states slice [64][72] bf16
#define SB_STR   72
#define QST_OFF  20992    // qs^T bf16 [32 agents][68 samples]
#define QST_STR  68
#define W1BS_OFF 23168    // w1l2b bf16 [2048]
#define Y_OFF    25216    // y[64][200]: [0,64) h1 | [64,128) h2 | [128,192) b1v->hidden
#define Y_STR    200
#define PBUF_OFF 0        // phase-B partials [4][64][72] — overlays wbuf+sb (dead)
#define PBUF_STR 72
#define PBUF_WV  (64 * 72)
#define QACC_OFF  38016   // f32[64]
#define QACC2_OFF 38144   // f32[64]
#define B2WV_OFF  38272   // f32[64]
#define SMEM_U16  38400

__device__ __forceinline__ float bf2f(u16 u) {
    u32 i = ((u32)u) << 16; float f;
    __builtin_memcpy(&f, &i, 4); return f;
}
__device__ __forceinline__ u16 f2bf(float f) {
    u32 i; __builtin_memcpy(&i, &f, 4);
    return (u16)((i + 0x8000u) >> 16);
}
__device__ __forceinline__ bf16x8 ld8(const u16* p) {
    return *reinterpret_cast<const bf16x8*>(p);
}
__device__ __forceinline__ bf16x8 cvt8(f32x4 a, f32x4 b) {
    bf16x8 r;
#pragma unroll
    for (int i = 0; i < 4; ++i) r[i]     = (short)f2bf(a[i]);
#pragma unroll
    for (int i = 0; i < 4; ++i) r[i + 4] = (short)f2bf(b[i]);
    return r;
}
// async global->LDS DMA, 16B per lane (dest = wave-uniform base + lane*16)
__device__ __forceinline__ void dma16(const void* g, void* l) {
    __builtin_amdgcn_global_load_lds(
        (const __attribute__((address_space(1))) u32*)g,
        (__attribute__((address_space(3))) u32*)l, 16, 0, 0);
}

__global__ __launch_bounds__(256) void cvt_weights(
    const float* __restrict__ w1l1w, const float* __restrict__ w2l1w,
    const float* __restrict__ b1w,   const float* __restrict__ b2l1w,
    const float* __restrict__ w1l2w, const float* __restrict__ w2l2w,
    u16* __restrict__ ws)
{
    int idx = blockIdx.x * 256 + threadIdx.x;
    const float* src; int off;
    if      (idx < OFF_W2L1)  { src = w1l1w; off = OFF_W1L1; }
    else if (idx < OFF_B1W)   { src = w2l1w; off = OFF_W2L1; }
    else if (idx < OFF_B2L1)  { src = b1w;   off = OFF_B1W;  }
    else if (idx < OFF_W1L2)  { src = b2l1w; off = OFF_B2L1; }
    else if (idx < OFF_W2L2)  { src = w1l2w; off = OFF_W1L2; }
    else if (idx < WS_TOTAL)  { src = w2l2w; off = OFF_W2L2; }
    else return;
    ws[idx] = f2bf(src[idx - off]);
}

// R1's verified work-split + R0's verified DMA staging:
//  Phase A (feature-split): wave w owns features [64w,64w+64) x ALL 64 samples.
//    Per K=64 slice: wave DMA-stages ITS 64 weight rows (8KB, XOR-swizzled,
//    R0 formulas) into its quarter of wbuf and reads ONLY those (4x less LDS
//    read than sample-split). States staged cooperatively [64][72] bf16.
//    R0's two-barrier serial discipline per slice.
//    wave 3 (hb feats 192..255) dots with b2l2w immediately -> qacc2.
//  Phase B (agent-split): wave w owns agents [8w,8w+8); per agent, DMA-stage
//    its 64 W1l2 rows into wave's wbuf quarter; hacc[st2][tp] partials over
//    ALL 64 samples; pbuf + cross-wave reduction -> hidden (elu), in y.
//  Phase C: per-wave 16 samples: w2 = |h2 @ W2l2^T + b| dot hidden -> qacc.
//  Phase D: out = qacc + qacc2 + b2l2b.
__global__ __launch_bounds__(256, 2) void qmix_kernel(
    const float* __restrict__ qs,    const float* __restrict__ st,
    const u16*  __restrict__ wsb,
    const float* __restrict__ w1l1b, const float* __restrict__ w1l2b,
    const float* __restrict__ w2l1b, const float* __restrict__ w2l2b,
    const float* __restrict__ b1b,   const float* __restrict__ b2l1b,
    const float* __restrict__ b2l2w, const float* __restrict__ b2l2b,
    float* __restrict__ out)
{
    __shared__ u16 smem[SMEM_U16];
    float* qaccF  = (float*)(smem + QACC_OFF);
    float* qacc2F = (float*)(smem + QACC2_OFF);
    float* b2wvF  = (float*)(smem + B2WV_OFF);

    const int t    = threadIdx.x;
    const int wave = t >> 6, lane = t & 63;
    const int m = lane & 15, quad = lane >> 4;
    const int rsub = lane >> 3, cch = lane & 7;
    const int sc = cch ^ rsub;          // XOR-swizzled source chunk (R0's formula)
    const int sbase = blockIdx.x * TB;

    // ---- prologue staging ----
    if (t < 64) b2wvF[t] = b2l2w[t];
    {   // qs -> bf16 transposed [agent][sample]
        const float* qp = qs + (size_t)sbase * NAG + t * 8;
        f32x4 q0 = *reinterpret_cast<const f32x4*>(qp);
        f32x4 q1 = *reinterpret_cast<const f32x4*>(qp + 4);
        const int s = t >> 2, a0 = (t & 3) * 8;
#pragma unroll
        for (int j = 0; j < 4; ++j) smem[QST_OFF + (a0 + j) * QST_STR + s]     = f2bf(q0[j]);
#pragma unroll
        for (int j = 0; j < 4; ++j) smem[QST_OFF + (a0 + 4 + j) * QST_STR + s] = f2bf(q1[j]);
        // w1l2b -> bf16
        f32x4 w0 = *reinterpret_cast<const f32x4*>(w1l2b + t * 8);
        f32x4 w1 = *reinterpret_cast<const f32x4*>(w1l2b + t * 8 + 4);
        *reinterpret_cast<bf16x8*>(&smem[W1BS_OFF + t * 8]) = cvt8(w0, w1);
    }

    // states staging: thread owns samples (ss1, ss1+32), chunk c8
    const int ss1 = t >> 3, c8 = t & 7;
    const float* stb = st + (size_t)sbase * STATE;

    // ---- Phase A: 8 slices of K=64, two-barrier serial staging ----
    f32x4 acc[4][4] = {};   // [sample-tile][feature-tile]
    for (int ks = 0; ks < 8; ++ks) {
        __syncthreads();   // prev slice fully consumed (also covers prologue LDS)
        // DMA own 64-row weight block, K-chunk ks (R0's swizzled staging)
#pragma unroll
        for (int j = 0; j < 8; ++j)
            dma16(wsb + (size_t)(wave * 64 + j * 8 + rsub) * STATE + ks * 64 + sc * 8,
                  &smem[WBUF_OFF + (wave * 64 + j * 8) * 64]);
        // stage states slice ks (coalesced f32 -> bf16)
        {
            const float* g1 = stb + (size_t)ss1 * STATE + ks * 64 + c8 * 8;
            const float* g2 = g1 + (size_t)32 * STATE;
            f32x4 a0 = *reinterpret_cast<const f32x4*>(g1);
            f32x4 a1 = *reinterpret_cast<const f32x4*>(g1 + 4);
            f32x4 a2 = *reinterpret_cast<const f32x4*>(g2);
            f32x4 a3 = *reinterpret_cast<const f32x4*>(g2 + 4);
            *reinterpret_cast<bf16x8*>(&smem[SB_OFF + ss1 * SB_STR + c8 * 8])        = cvt8(a0, a1);
            *reinterpret_cast<bf16x8*>(&smem[SB_OFF + (ss1 + 32) * SB_STR + c8 * 8]) = cvt8(a2, a3);
        }
        __builtin_amdgcn_s_waitcnt(0);
        __syncthreads();   // slice staged (all waves)
        // compute: weight fragments once (reused across 4 sample-tiles)
        bf16x8 wfr[4][2];
#pragma unroll
        for (int ot = 0; ot < 4; ++ot) {
            const int brow = wave * 64 + ot * 16 + m;
            wfr[ot][0] = ld8(&smem[WBUF_OFF + brow * 64 + ((quad ^ (brow & 7))) * 8]);
            wfr[ot][1] = ld8(&smem[WBUF_OFF + brow * 64 + (((quad + 4) ^ (brow & 7))) * 8]);
        }
#pragma unroll
        for (int st2 = 0; st2 < 4; ++st2) {
            const int row = st2 * 16 + m;
            bf16x8 af0 = ld8(&smem[SB_OFF + row * SB_STR + quad * 8]);
            bf16x8 af1 = ld8(&smem[SB_OFF + row * SB_STR + (quad + 4) * 8]);
#pragma unroll
            for (int ot = 0; ot < 4; ++ot)
                acc[st2][ot] = __builtin_amdgcn_mfma_f32_16x16x32_bf16(af0, wfr[ot][0], acc[st2][ot], 0, 0, 0);
#pragma unroll
            for (int ot = 0; ot < 4; ++ot)
                acc[st2][ot] = __builtin_amdgcn_mfma_f32_16x16x32_bf16(af1, wfr[ot][1], acc[st2][ot], 0, 0, 0);
        }
    }

    // ---- Phase A epilogue (R1's, verified): wave = feature group ----
    if (wave < 3) {
        const float* barr = (wave == 0) ? w1l1b : (wave == 1) ? w2l1b : b1b;
        const bool isrelu = (wave != 2);
        float wb[4];
#pragma unroll
        for (int ot = 0; ot < 4; ++ot) wb[ot] = barr[ot * 16 + m];
#pragma unroll
        for (int st2 = 0; st2 < 4; ++st2)
#pragma unroll
            for (int ot = 0; ot < 4; ++ot)
#pragma unroll
                for (int r = 0; r < 4; ++r) {
                    float v = acc[st2][ot][r] + wb[ot];
                    if (isrelu) v = fmaxf(v, 0.f);
                    smem[Y_OFF + (st2 * 16 + quad * 4 + r) * Y_STR + wave * 64 + ot * 16 + m] = f2bf(v);
                }
    } else {
        // hb = relu(states @ b2l1 + b) dotted with b2l2w -> qacc2
        float wb[4], bw[4];
#pragma unroll
        for (int ot = 0; ot < 4; ++ot) wb[ot] = b2l1b[ot * 16 + m];
#pragma unroll
        for (int ot = 0; ot < 4; ++ot) bw[ot] = b2wvF[ot * 16 + m];
#pragma unroll
        for (int st2 = 0; st2 < 4; ++st2)
#pragma unroll
            for (int r = 0; r < 4; ++r) {
                float pd = 0.f;
#pragma unroll
                for (int ot = 0; ot < 4; ++ot)
                    pd += fmaxf(acc[st2][ot][r] + wb[ot], 0.f) * bw[ot];
#pragma unroll
                for (int off = 1; off < 16; off <<= 1) pd += __shfl_xor(pd, off, 64);
                if (m == 0) qacc2F[st2 * 16 + quad * 4 + r] = pd;
            }
    }
    __syncthreads();   // y + qacc2 ready

    // ---- Phase B: wave w owns agents [8w, 8w+8) x all 64 samples ----
    bf16x8 h1f[4][2];
#pragma unroll
    for (int st2 = 0; st2 < 4; ++st2) {
        h1f[st2][0] = ld8(&smem[Y_OFF + (st2 * 16 + m) * Y_STR + quad * 8]);
        h1f[st2][1] = ld8(&smem[Y_OFF + (st2 * 16 + m) * Y_STR + 32 + quad * 8]);
    }

    f32x4 hacc[4][4] = {};   // [sample-tile][embed-tile]
    for (int j = 0; j < 8; ++j) {
        __syncthreads();   // pace waves; wbuf reuse safe
        const int a = wave * 8 + j;
        // DMA agent a's 64 W1l2 rows into wave's wbuf quarter (same swizzle)
#pragma unroll
        for (int jj = 0; jj < 8; ++jj)
            dma16(wsb + OFF_W1L2 + (size_t)(a * 64 + jj * 8 + rsub) * EMBED + sc * 8,
                  &smem[WBUF_OFF + (wave * 64 + jj * 8) * 64]);
        __builtin_amdgcn_s_waitcnt(0);
        __syncthreads();
        bf16x8 wf[4][2];
#pragma unroll
        for (int tp = 0; tp < 4; ++tp) {
            const int brow = wave * 64 + tp * 16 + m;
            wf[tp][0] = ld8(&smem[WBUF_OFF + brow * 64 + ((quad ^ (brow & 7))) * 8]);
            wf[tp][1] = ld8(&smem[WBUF_OFF + brow * 64 + (((quad + 4) ^ (brow & 7))) * 8]);
        }
        float bias[4];
#pragma unroll
        for (int tp = 0; tp < 4; ++tp) bias[tp] = bf2f(smem[W1BS_OFF + a * EMBED + tp * 16 + m]);
#pragma unroll
        for (int st2 = 0; st2 < 4; ++st2) {
            u16x4 qv = *reinterpret_cast<const u16x4*>(
                &smem[QST_OFF + a * QST_STR + st2 * 16 + quad * 4]);
#pragma unroll
            for (int tp = 0; tp < 4; ++tp) {
                f32x4 p = {};
                p = __builtin_amdgcn_mfma_f32_16x16x32_bf16(h1f[st2][0], wf[tp][0], p, 0, 0, 0);
                p = __builtin_amdgcn_mfma_f32_16x16x32_bf16(h1f[st2][1], wf[tp][1], p, 0, 0, 0);
#pragma unroll
                for (int r = 0; r < 4; ++r)
                    hacc[st2][tp][r] += bf2f((u16)qv[r]) * fabsf(p[r] + bias[tp]);
            }
        }
    }
    __syncthreads();   // ALL waves done with wbuf -> pbuf overlay safe

    // per-wave partials (R1's, verified)
#pragma unroll
    for (int st2 = 0; st2 < 4; ++st2)
#pragma unroll
        for (int tp = 0; tp < 4; ++tp)
#pragma unroll
            for (int r = 0; r < 4; ++r)
                smem[PBUF_OFF + wave * PBUF_WV
                     + (st2 * 16 + quad * 4 + r) * PBUF_STR + tp * 16 + m]
                    = f2bf(hacc[st2][tp][r]);
    __syncthreads();   // partials in

    // ---- reduction: hidden = elu(sum_waves pbuf + b1v), in place over b1v ----
    {
        const int s  = wave * 16 + (lane & 15);
        const int eb = (lane >> 4) * 16;
        float v[16];
#pragma unroll
        for (int jj = 0; jj < 16; ++jj) v[jj] = 0.f;
#pragma unroll
        for (int pw = 0; pw < 4; ++pw) {
#pragma unroll
            for (int c = 0; c < 4; ++c) {
                u16x4 x = *reinterpret_cast<const u16x4*>(
                    &smem[PBUF_OFF + pw * PBUF_WV + s * PBUF_STR + eb + c * 4]);
#pragma unroll
                for (int jj = 0; jj < 4; ++jj) v[c * 4 + jj] += bf2f((u16)x[jj]);
            }
        }
        bf16x8 bv0 = ld8(&smem[Y_OFF + s * Y_STR + 128 + eb]);
        bf16x8 bv1 = ld8(&smem[Y_OFF + s * Y_STR + 128 + eb + 8]);
        bf16x8 o0, o1;
#pragma unroll
        for (int jj = 0; jj < 8; ++jj) {
            float h0 = v[jj] + bf2f((u16)bv0[jj]);
            h0 = (h0 > 0.f) ? h0 : (__expf(h0) - 1.f);
            o0[jj] = (short)f2bf(h0);
            float h1 = v[8 + jj] + bf2f((u16)bv1[jj]);
            h1 = (h1 > 0.f) ? h1 : (__expf(h1) - 1.f);
            o1[jj] = (short)f2bf(h1);
        }
        *reinterpret_cast<bf16x8*>(&smem[Y_OFF + s * Y_STR + 128 + eb])     = o0;
        *reinterpret_cast<bf16x8*>(&smem[Y_OFF + s * Y_STR + 128 + eb + 8]) = o1;
    }
    __syncthreads();   // hidden ready

    // ---- Phase C (R1's, verified): 16 samples/wave ----
    {
        const int s0 = wave * 16;
        bf16x8 h2f0 = ld8(&smem[Y_OFF + (s0 + m) * Y_STR + 64 + quad * 8]);
        bf16x8 h2f1 = ld8(&smem[Y_OFF + (s0 + m) * Y_STR + 96 + quad * 8]);

        f32x4 qp = {};
#pragma unroll
        for (int tp = 0; tp < 4; ++tp) {
            const u16* wc = wsb + OFF_W2L2 + (size_t)(tp * 16 + m) * EMBED + quad * 8;
            bf16x8 c0 = ld8(wc);
            bf16x8 c1 = ld8(wc + 32);
            f32x4 p = {};
            p = __builtin_amdgcn_mfma_f32_16x16x32_bf16(h2f0, c0, p, 0, 0, 0);
            p = __builtin_amdgcn_mfma_f32_16x16x32_bf16(h2f1, c1, p, 0, 0, 0);
            const float bias = w2l2b[tp * 16 + m];
#pragma unroll
            for (int r = 0; r < 4; ++r)
                qp[r] += bf2f(smem[Y_OFF + (s0 + quad * 4 + r) * Y_STR + 128 + tp * 16 + m])
                         * fabsf(p[r] + bias);
        }
#pragma unroll
        for (int off = 1; off < 16; off <<= 1) {
#pragma unroll
            for (int r = 0; r < 4; ++r) qp[r] += __shfl_xor(qp[r], off, 64);
        }
        if (m == 0) {
#pragma unroll
            for (int r = 0; r < 4; ++r) qaccF[s0 + quad * 4 + r] = qp[r];
        }
    }
    __syncthreads();   // qacc ready

    // ---- Phase D ----
    if (t < TB) out[sbase + t] = qaccF[t] + qacc2F[t] + b2l2b[0];
}

extern "C" void kernel_launch(void* const* d_in, const int* in_sizes, int n_in,
                              void* d_out, int out_size, void* d_ws, size_t ws_size,
                              hipStream_t stream)
{
    const float* qs    = (const float*)d_in[0];
    const float* st    = (const float*)d_in[1];
    const float* w1l1w = (const float*)d_in[2];
    const float* w1l1b = (const float*)d_in[3];
    const float* w1l2w = (const float*)d_in[4];
    const float* w1l2b = (const float*)d_in[5];
    const float* w2l1w = (const float*)d_in[6];
    const float* w2l1b = (const float*)d_in[7];
    const float* w2l2w = (const float*)d_in[8];
    const float* w2l2b = (const float*)d_in[9];
    const float* b1w   = (const float*)d_in[10];
    const float* b1b   = (const float*)d_in[11];
    const float* b2l1w = (const float*)d_in[12];
    const float* b2l1b = (const float*)d_in[13];
    const float* b2l2w = (const float*)d_in[14];
    const float* b2l2b = (const float*)d_in[15];

    u16* wsb = (u16*)d_ws;

    cvt_weights<<<(WS_TOTAL + 255) / 256, 256, 0, stream>>>(
        w1l1w, w2l1w, b1w, b2l1w, w1l2w, w2l2w, wsb);

    int B = in_sizes[0] / NAG;        // 32768
    int grid = B / TB;                // 512 = 2 blocks/CU, single round
    qmix_kernel<<<grid, 256, 0, stream>>>(
        qs, st, wsb,
        w1l1b, w1l2b, w2l1b, w2l2b, b1b, b2l1b, b2l2w, b2l2b,
        (float*)d_out);
}

// Round 8
// 145.287 us; speedup vs baseline: 1.2729x; 1.0153x over previous
//
#include <hip/hip_runtime.h>

typedef unsigned short u16;
typedef unsigned int u32;
typedef short bf16x8 __attribute__((ext_vector_type(8)));
typedef float f32x4 __attribute__((ext_vector_type(4)));
typedef u16 u16x4 __attribute__((ext_vector_type(4)));

#define NAG 32
#define STATE 512
#define EMBED 64
#define TB 64   // samples per block; 256 threads (4 waves); grid = 512 = 2 blocks/CU

// d_ws bf16 layout (u16 element offsets).
#define OFF_W1L1 0
#define OFF_W2L1 32768
#define OFF_B1W  65536
#define OFF_B2L1 98304
#define OFF_W1L2 131072
#define OFF_W2L2 262144
#define WS_TOTAL 266240

// smem layout (u16 offsets). Total 38912 u16 = 76 KB -> 2 blocks/CU.
#define WBUF_OFF 0            // [2][128][64] double-buffered weight stages
#define WBUF_SZ  8192
#define SB_OFF   16384        // [2][64][72] state K-slices (double-buffered)
#define SB_STR   72
#define SB_BUF   4608
#define B1V_OFF  20992        // = sb[1] region after phase A: b1v -> hidden [64][72]
#define QST_OFF  25600        // qs^T bf16 [32][68]
#define QST_STR  68
#define W1BS_OFF 27776        // w1l2b bf16 [2048]
#define Y_OFF    29824        // y[64][136]: [0,64) h1 | [64,128) h2
#define Y_STR    136
#define PBUF_OFF 0            // phase-B partials [4][64][72] — overlays wbuf+sb0 (dead)
#define PBUF_STR 72
#define PBUF_WV  4608
#define QACC_OFF  38528       // f32[64]
#define QACC2_OFF 38656       // f32[64]
#define B2WV_OFF  38784       // f32[64]
#define SMEM_U16  38912

__device__ __forceinline__ float bf2f(u16 u) {
    u32 i = ((u32)u) << 16; float f;
    __builtin_memcpy(&f, &i, 4); return f;
}
__device__ __forceinline__ u16 f2bf(float f) {
    u32 i; __builtin_memcpy(&i, &f, 4);
    return (u16)((i + 0x8000u) >> 16);
}
__device__ __forceinline__ bf16x8 ld8(const u16* p) {
    return *reinterpret_cast<const bf16x8*>(p);
}
__device__ __forceinline__ bf16x8 cvt8(f32x4 a, f32x4 b) {
    bf16x8 r;
#pragma unroll
    for (int i = 0; i < 4; ++i) r[i]     = (short)f2bf(a[i]);
#pragma unroll
    for (int i = 0; i < 4; ++i) r[i + 4] = (short)f2bf(b[i]);
    return r;
}
// async global->LDS DMA, 16B per lane (dest = wave-uniform base + lane*16)
__device__ __forceinline__ void dma16(const void* g, void* l) {
    __builtin_amdgcn_global_load_lds(
        (const __attribute__((address_space(1))) u32*)g,
        (__attribute__((address_space(3))) u32*)l, 16, 0, 0);
}

__global__ __launch_bounds__(256) void cvt_weights(
    const float* __restrict__ w1l1w, const float* __restrict__ w2l1w,
    const float* __restrict__ b1w,   const float* __restrict__ b2l1w,
    const float* __restrict__ w1l2w, const float* __restrict__ w2l2w,
    u16* __restrict__ ws)
{
    int idx = blockIdx.x * 256 + threadIdx.x;
    const float* src; int off;
    if      (idx < OFF_W2L1)  { src = w1l1w; off = OFF_W1L1; }
    else if (idx < OFF_B1W)   { src = w2l1w; off = OFF_W2L1; }
    else if (idx < OFF_B2L1)  { src = b1w;   off = OFF_B1W;  }
    else if (idx < OFF_W1L2)  { src = b2l1w; off = OFF_B2L1; }
    else if (idx < OFF_W2L2)  { src = w1l2w; off = OFF_W1L2; }
    else if (idx < WS_TOTAL)  { src = w2l2w; off = OFF_W2L2; }
    else return;
    ws[idx] = f2bf(src[idx - off]);
}

// R7's verified work-split/swizzle + T3-minimum pipelining:
//  32-row double-buffered stages; DMA for stage k+1 issued BEFORE computing
//  stage k; ONE __syncthreads per stage (its implicit drain lands after the
//  compute). States reg-loaded at even stages, LDS-written at odd (T14 split).
//  Phase A (16 stages: K-slice ks = s>>1, feature-half h = s&1): wave w owns
//    features [64w,64w+64); per stage stages rows [64w+32h, +32) x K=64.
//    wave2's b1v -> sb1 region (post-A dead); wave3 -> hbq dot -> qacc2.
//  Phase B (16 stages: agent j = s>>1 of wave's 8, half h = s&1).
//  Then: pbuf partial reduce -> hidden=elu (in sb1 region), Phase C, D (R7).
__global__ __launch_bounds__(256, 2) void qmix_kernel(
    const float* __restrict__ qs,    const float* __restrict__ st,
    const u16*  __restrict__ wsb,
    const float* __restrict__ w1l1b, const float* __restrict__ w1l2b,
    const float* __restrict__ w2l1b, const float* __restrict__ w2l2b,
    const float* __restrict__ b1b,   const float* __restrict__ b2l1b,
    const float* __restrict__ b2l2w, const float* __restrict__ b2l2b,
    float* __restrict__ out)
{
    __shared__ u16 smem[SMEM_U16];
    float* qaccF  = (float*)(smem + QACC_OFF);
    float* qacc2F = (float*)(smem + QACC2_OFF);
    float* b2wvF  = (float*)(smem + B2WV_OFF);

    const int t    = threadIdx.x;
    const int wave = t >> 6, lane = t & 63;
    const int m = lane & 15, quad = lane >> 4;
    const int r8 = lane >> 3, c8l = lane & 7;
    const int scx = c8l ^ r8;            // XOR-swizzled source chunk (row-key = r8)
    const int sbase = blockIdx.x * TB;

    // ---- prologue staging ----
    if (t < 64) b2wvF[t] = b2l2w[t];
    {   // qs -> bf16 transposed [agent][sample]
        const float* qp = qs + (size_t)sbase * NAG + t * 8;
        f32x4 q0 = *reinterpret_cast<const f32x4*>(qp);
        f32x4 q1 = *reinterpret_cast<const f32x4*>(qp + 4);
        const int s = t >> 2, a0 = (t & 3) * 8;
#pragma unroll
        for (int j = 0; j < 4; ++j) smem[QST_OFF + (a0 + j) * QST_STR + s]     = f2bf(q0[j]);
#pragma unroll
        for (int j = 0; j < 4; ++j) smem[QST_OFF + (a0 + 4 + j) * QST_STR + s] = f2bf(q1[j]);
        // w1l2b -> bf16
        f32x4 w0 = *reinterpret_cast<const f32x4*>(w1l2b + t * 8);
        f32x4 w1 = *reinterpret_cast<const f32x4*>(w1l2b + t * 8 + 4);
        *reinterpret_cast<bf16x8*>(&smem[W1BS_OFF + t * 8]) = cvt8(w0, w1);
    }

    // states: thread owns samples (ss1, ss1+32), chunk c8
    const int ss1 = t >> 3, c8 = t & 7;
    const float* stb = st + (size_t)sbase * STATE;
    {   // slice 0 -> sb0
        const float* g1 = stb + (size_t)ss1 * STATE + c8 * 8;
        const float* g2 = g1 + (size_t)32 * STATE;
        f32x4 a0 = *reinterpret_cast<const f32x4*>(g1);
        f32x4 a1 = *reinterpret_cast<const f32x4*>(g1 + 4);
        f32x4 a2 = *reinterpret_cast<const f32x4*>(g2);
        f32x4 a3 = *reinterpret_cast<const f32x4*>(g2 + 4);
        *reinterpret_cast<bf16x8*>(&smem[SB_OFF + ss1 * SB_STR + c8 * 8])        = cvt8(a0, a1);
        *reinterpret_cast<bf16x8*>(&smem[SB_OFF + (ss1 + 32) * SB_STR + c8 * 8]) = cvt8(a2, a3);
    }
    // DMA A stage 0: weight rows [64w, 64w+32), K 0..63 -> buf0 rows [32w, +32)
#pragma unroll
    for (int j = 0; j < 4; ++j)
        dma16(wsb + (size_t)(wave * 64 + j * 8 + r8) * STATE + scx * 8,
              &smem[WBUF_OFF + (wave * 32 + j * 8) * 64]);
    __syncthreads();   // stage 0 + prologue staged

    // ---- Phase A: 16 pipelined stages ----
    f32x4 acc[4][4] = {};   // [sample-tile][feature-tile 0..3]
    f32x4 sa[4];            // states prefetch regs (live across one stage)
#pragma unroll
    for (int s = 0; s < 16; ++s) {
        const int ks = s >> 1, h = s & 1, cur = s & 1, nxt = cur ^ 1;
        // 1) prefetch next stage's weights into buf[nxt]
        if (s < 15) {
            const int ks2 = (s + 1) >> 1, h2 = (s + 1) & 1;
#pragma unroll
            for (int j = 0; j < 4; ++j)
                dma16(wsb + (size_t)(wave * 64 + h2 * 32 + j * 8 + r8) * STATE + ks2 * 64 + scx * 8,
                      &smem[WBUF_OFF + nxt * WBUF_SZ + (wave * 32 + j * 8) * 64]);
        } else {
            // B stage 0: agent 8w, rows 0..31
#pragma unroll
            for (int j = 0; j < 4; ++j)
                dma16(wsb + OFF_W1L2 + (size_t)(wave * 8 * 64 + j * 8 + r8) * EMBED + scx * 8,
                      &smem[WBUF_OFF + nxt * WBUF_SZ + (wave * 32 + j * 8) * 64]);
        }
        // 2) states pipeline: issue loads at even stages
        if (h == 0 && ks < 7) {
            const float* g1 = stb + (size_t)ss1 * STATE + (ks + 1) * 64 + c8 * 8;
            const float* g2 = g1 + (size_t)32 * STATE;
            sa[0] = *reinterpret_cast<const f32x4*>(g1);
            sa[1] = *reinterpret_cast<const f32x4*>(g1 + 4);
            sa[2] = *reinterpret_cast<const f32x4*>(g2);
            sa[3] = *reinterpret_cast<const f32x4*>(g2 + 4);
        }
        // 3) compute stage s from buf[cur] + sb[ks&1]
        const u16* wb  = &smem[WBUF_OFF + cur * WBUF_SZ];
        const u16* sbc = &smem[SB_OFF + (ks & 1) * SB_BUF];
        bf16x8 wf[2][2];
#pragma unroll
        for (int o = 0; o < 2; ++o) {
            const int br = wave * 32 + o * 16 + m;
            wf[o][0] = ld8(&wb[br * 64 + ((quad ^ (m & 7))) * 8]);
            wf[o][1] = ld8(&wb[br * 64 + (((quad + 4) ^ (m & 7))) * 8]);
        }
#pragma unroll
        for (int st2 = 0; st2 < 4; ++st2) {
            const int row = st2 * 16 + m;
            bf16x8 af0 = ld8(&sbc[row * SB_STR + quad * 8]);
            bf16x8 af1 = ld8(&sbc[row * SB_STR + (quad + 4) * 8]);
#pragma unroll
            for (int o = 0; o < 2; ++o) {
                acc[st2][h * 2 + o] = __builtin_amdgcn_mfma_f32_16x16x32_bf16(af0, wf[o][0], acc[st2][h * 2 + o], 0, 0, 0);
                acc[st2][h * 2 + o] = __builtin_amdgcn_mfma_f32_16x16x32_bf16(af1, wf[o][1], acc[st2][h * 2 + o], 0, 0, 0);
            }
        }
        // 4) states pipeline: write at odd stages into sb[(ks+1)&1]
        if (h == 1 && ks < 7) {
            u16* dst = &smem[SB_OFF + ((ks + 1) & 1) * SB_BUF];
            *reinterpret_cast<bf16x8*>(&dst[ss1 * SB_STR + c8 * 8])        = cvt8(sa[0], sa[1]);
            *reinterpret_cast<bf16x8*>(&dst[(ss1 + 32) * SB_STR + c8 * 8]) = cvt8(sa[2], sa[3]);
        }
        __syncthreads();   // next buffer staged; this buffer reusable
    }

    // ---- Phase A epilogue (after final barrier: sb reads done everywhere) ----
    if (wave < 2) {
        const float* barr = (wave == 0) ? w1l1b : w2l1b;
        float wb4[4];
#pragma unroll
        for (int ot = 0; ot < 4; ++ot) wb4[ot] = barr[ot * 16 + m];
#pragma unroll
        for (int st2 = 0; st2 < 4; ++st2)
#pragma unroll
            for (int ot = 0; ot < 4; ++ot)
#pragma unroll
                for (int r = 0; r < 4; ++r) {
                    float v = fmaxf(acc[st2][ot][r] + wb4[ot], 0.f);
                    smem[Y_OFF + (st2 * 16 + quad * 4 + r) * Y_STR + wave * 64 + ot * 16 + m] = f2bf(v);
                }
    } else if (wave == 2) {
        // b1v (linear) -> sb1 region
        float wb4[4];
#pragma unroll
        for (int ot = 0; ot < 4; ++ot) wb4[ot] = b1b[ot * 16 + m];
#pragma unroll
        for (int st2 = 0; st2 < 4; ++st2)
#pragma unroll
            for (int ot = 0; ot < 4; ++ot)
#pragma unroll
                for (int r = 0; r < 4; ++r)
                    smem[B1V_OFF + (st2 * 16 + quad * 4 + r) * SB_STR + ot * 16 + m]
                        = f2bf(acc[st2][ot][r] + wb4[ot]);
    } else {
        // hb = relu(. + b) dotted with b2l2w -> qacc2
        float wb4[4], bw[4];
#pragma unroll
        for (int ot = 0; ot < 4; ++ot) wb4[ot] = b2l1b[ot * 16 + m];
#pragma unroll
        for (int ot = 0; ot < 4; ++ot) bw[ot] = b2wvF[ot * 16 + m];
#pragma unroll
        for (int st2 = 0; st2 < 4; ++st2)
#pragma unroll
            for (int r = 0; r < 4; ++r) {
                float pd = 0.f;
#pragma unroll
                for (int ot = 0; ot < 4; ++ot)
                    pd += fmaxf(acc[st2][ot][r] + wb4[ot], 0.f) * bw[ot];
#pragma unroll
                for (int off = 1; off < 16; off <<= 1) pd += __shfl_xor(pd, off, 64);
                if (m == 0) qacc2F[st2 * 16 + quad * 4 + r] = pd;
            }
    }
    __syncthreads();   // y + b1v + qacc2 visible (B0 DMA drained at A15 barrier)

    // ---- Phase B: 16 pipelined stages; wave w owns agents [8w, 8w+8) ----
    bf16x8 h1f[4][2];
#pragma unroll
    for (int st2 = 0; st2 < 4; ++st2) {
        h1f[st2][0] = ld8(&smem[Y_OFF + (st2 * 16 + m) * Y_STR + quad * 8]);
        h1f[st2][1] = ld8(&smem[Y_OFF + (st2 * 16 + m) * Y_STR + 32 + quad * 8]);
    }

    f32x4 hacc[4][4] = {};   // [sample-tile][embed-tile]
#pragma unroll
    for (int s = 0; s < 16; ++s) {
        const int jb = s >> 1, hb = s & 1, cur = s & 1, nxt = cur ^ 1;
        const int a = wave * 8 + jb;
        if (s < 15) {
            const int jb2 = (s + 1) >> 1, hb2 = (s + 1) & 1;
            const int a2 = wave * 8 + jb2;
#pragma unroll
            for (int j = 0; j < 4; ++j)
                dma16(wsb + OFF_W1L2 + (size_t)(a2 * 64 + hb2 * 32 + j * 8 + r8) * EMBED + scx * 8,
                      &smem[WBUF_OFF + nxt * WBUF_SZ + (wave * 32 + j * 8) * 64]);
        }
        const u16* wb = &smem[WBUF_OFF + cur * WBUF_SZ];
        bf16x8 wf[2][2];
#pragma unroll
        for (int o = 0; o < 2; ++o) {
            const int br = wave * 32 + o * 16 + m;
            wf[o][0] = ld8(&wb[br * 64 + ((quad ^ (m & 7))) * 8]);
            wf[o][1] = ld8(&wb[br * 64 + (((quad + 4) ^ (m & 7))) * 8]);
        }
        float bias2[2];
#pragma unroll
        for (int o = 0; o < 2; ++o)
            bias2[o] = bf2f(smem[W1BS_OFF + a * EMBED + (hb * 2 + o) * 16 + m]);
#pragma unroll
        for (int st2 = 0; st2 < 4; ++st2) {
            u16x4 qv = *reinterpret_cast<const u16x4*>(
                &smem[QST_OFF + a * QST_STR + st2 * 16 + quad * 4]);
#pragma unroll
            for (int o = 0; o < 2; ++o) {
                f32x4 p = {};
                p = __builtin_amdgcn_mfma_f32_16x16x32_bf16(h1f[st2][0], wf[o][0], p, 0, 0, 0);
                p = __builtin_amdgcn_mfma_f32_16x16x32_bf16(h1f[st2][1], wf[o][1], p, 0, 0, 0);
#pragma unroll
                for (int r = 0; r < 4; ++r)
                    hacc[st2][hb * 2 + o][r] += bf2f((u16)qv[r]) * fabsf(p[r] + bias2[o]);
            }
        }
        __syncthreads();   // next buffer staged; this buffer reusable
    }

    // ---- pbuf partials (overlay wbuf+sb0; safe after B15 barrier) ----
#pragma unroll
    for (int st2 = 0; st2 < 4; ++st2)
#pragma unroll
        for (int tp = 0; tp < 4; ++tp)
#pragma unroll
            for (int r = 0; r < 4; ++r)
                smem[PBUF_OFF + wave * PBUF_WV
                     + (st2 * 16 + quad * 4 + r) * PBUF_STR + tp * 16 + m]
                    = f2bf(hacc[st2][tp][r]);
    __syncthreads();   // partials in

    // ---- reduction: hidden = elu(sum_waves pbuf + b1v), in place in sb1 region ----
    {
        const int s  = wave * 16 + (lane & 15);
        const int eb = (lane >> 4) * 16;
        float v[16];
#pragma unroll
        for (int jj = 0; jj < 16; ++jj) v[jj] = 0.f;
#pragma unroll
        for (int pw = 0; pw < 4; ++pw) {
#pragma unroll
            for (int c = 0; c < 4; ++c) {
                u16x4 x = *reinterpret_cast<const u16x4*>(
                    &smem[PBUF_OFF + pw * PBUF_WV + s * PBUF_STR + eb + c * 4]);
#pragma unroll
                for (int jj = 0; jj < 4; ++jj) v[c * 4 + jj] += bf2f((u16)x[jj]);
            }
        }
        bf16x8 bv0 = ld8(&smem[B1V_OFF + s * SB_STR + eb]);
        bf16x8 bv1 = ld8(&smem[B1V_OFF + s * SB_STR + eb + 8]);
        bf16x8 o0, o1;
#pragma unroll
        for (int jj = 0; jj < 8; ++jj) {
            float h0 = v[jj] + bf2f((u16)bv0[jj]);
            h0 = (h0 > 0.f) ? h0 : (__expf(h0) - 1.f);
            o0[jj] = (short)f2bf(h0);
            float h1 = v[8 + jj] + bf2f((u16)bv1[jj]);
            h1 = (h1 > 0.f) ? h1 : (__expf(h1) - 1.f);
            o1[jj] = (short)f2bf(h1);
        }
        *reinterpret_cast<bf16x8*>(&smem[B1V_OFF + s * SB_STR + eb])     = o0;
        *reinterpret_cast<bf16x8*>(&smem[B1V_OFF + s * SB_STR + eb + 8]) = o1;
    }
    __syncthreads();   // hidden ready

    // ---- Phase C: 16 samples/wave: w2 = |h2 @ W2l2^T + b| dot hidden ----
    {
        const int s0 = wave * 16;
        bf16x8 h2f0 = ld8(&smem[Y_OFF + (s0 + m) * Y_STR + 64 + quad * 8]);
        bf16x8 h2f1 = ld8(&smem[Y_OFF + (s0 + m) * Y_STR + 96 + quad * 8]);

        f32x4 qp = {};
#pragma unroll
        for (int tp = 0; tp < 4; ++tp) {
            const u16* wc = wsb + OFF_W2L2 + (size_t)(tp * 16 + m) * EMBED + quad * 8;
            bf16x8 c0 = ld8(wc);
            bf16x8 c1 = ld8(wc + 32);
            f32x4 p = {};
            p = __builtin_amdgcn_mfma_f32_16x16x32_bf16(h2f0, c0, p, 0, 0, 0);
            p = __builtin_amdgcn_mfma_f32_16x16x32_bf16(h2f1, c1, p, 0, 0, 0);
            const float bias = w2l2b[tp * 16 + m];
#pragma unroll
            for (int r = 0; r < 4; ++r)
                qp[r] += bf2f(smem[B1V_OFF + (s0 + quad * 4 + r) * SB_STR + tp * 16 + m])
                         * fabsf(p[r] + bias);
        }
#pragma unroll
        for (int off = 1; off < 16; off <<= 1) {
#pragma unroll
            for (int r = 0; r < 4; ++r) qp[r] += __shfl_xor(qp[r], off, 64);
        }
        if (m == 0) {
#pragma unroll
            for (int r = 0; r < 4; ++r) qaccF[s0 + quad * 4 + r] = qp[r];
        }
    }
    __syncthreads();   // qacc ready

    // ---- Phase D ----
    if (t < TB) out[sbase + t] = qaccF[t] + qacc2F[t] + b2l2b[0];
}

extern "C" void kernel_launch(void* const* d_in, const int* in_sizes, int n_in,
                              void* d_out, int out_size, void* d_ws, size_t ws_size,
                              hipStream_t stream)
{
    const float* qs    = (const float*)d_in[0];
    const float* st    = (const float*)d_in[1];
    const float* w1l1w = (const float*)d_in[2];
    const float* w1l1b = (const float*)d_in[3];
    const float* w1l2w = (const float*)d_in[4];
    const float* w1l2b = (const float*)d_in[5];
    const float* w2l1w = (const float*)d_in[6];
    const float* w2l1b = (const float*)d_in[7];
    const float* w2l2w = (const float*)d_in[8];
    const float* w2l2b = (const float*)d_in[9];
    const float* b1w   = (const float*)d_in[10];
    const float* b1b   = (const float*)d_in[11];
    const float* b2l1w = (const float*)d_in[12];
    const float* b2l1b = (const float*)d_in[13];
    const float* b2l2w = (const float*)d_in[14];
    const float* b2l2b = (const float*)d_in[15];

    u16* wsb = (u16*)d_ws;

    cvt_weights<<<(WS_TOTAL + 255) / 256, 256, 0, stream>>>(
        w1l1w, w2l1w, b1w, b2l1w, w1l2w, w2l2w, wsb);

    int B = in_sizes[0] / NAG;        // 32768
    int grid = B / TB;                // 512 = 2 blocks/CU, single round
    qmix_kernel<<<grid, 256, 0, stream>>>(
        qs, st, wsb,
        w1l1b, w1l2b, w2l1b, w2l2b, b1b, b2l1b, b2l2w, b2l2b,
        (float*)d_out);
}